// Round 11
// baseline (6996.696 us; speedup 1.0000x reference)
//
#include <hip/hip_runtime.h>
#include <hip/hip_bf16.h>
#include <math.h>

typedef unsigned short u16;
typedef __attribute__((ext_vector_type(4))) float f32x4;
typedef __attribute__((ext_vector_type(8))) short s16x8;

#define BB  512
#define TT  120
#define LAT 292
#define HH1 701
#define HH3 901
#define H1P 704
#define H3P 960
#define CH  35
#define NSTEP (TT + 3)
#define STEP_BARS 32

// ws layout (bytes)
static const size_t O_X    = 0;                     // 512*292*4
static const size_t O_XP1  = 598016;                // 512*2112*4 (f32)
static const size_t O_H1B  = 14622720;              // 2*512*704*2
static const size_t O_H2B  = 16064512;              // 2*512*704*2
static const size_t O_H3B  = 17506304;              // 2*512*960*2
static const size_t O_WHT1 = 19472384;              // 2112*704*2
static const size_t O_WIT2 = 22446080;              // 2112*704*2
static const size_t O_WHT2 = 25419776;              // 2112*704*2
static const size_t O_WIT3 = 28393472;              // 2816*704*2
static const size_t O_WHT3 = 32358400;              // 2816*960*2
static const size_t O_WOT  = 37765120;              // 64*960*2
static const size_t O_TAB  = 37888000;              // 256*4
static const size_t O_CNT  = 37889024;              // NSTEP*4
static const size_t ZERO_HB = 4849664;              // O_H1B..O_H3B end

static __device__ __forceinline__ u16 f2b(float f){
  union { float f; unsigned int i; } v; v.f = f;
  unsigned int x = v.i;
  return (u16)((x + 0x7FFFu + ((x >> 16) & 1u)) >> 16);
}

// async 16B global->LDS. aux=0: cached (weights). aux=17 (SC0|SC1): coherent, bypass L2 (h state).
#define GLLB(g, l) __builtin_amdgcn_global_load_lds( \
    (const __attribute__((address_space(1))) unsigned int*)(g), \
    (__attribute__((address_space(3))) unsigned int*)(l), 16, 0, 0)
#define GLLA(g, l) __builtin_amdgcn_global_load_lds( \
    (const __attribute__((address_space(1))) unsigned int*)(g), \
    (__attribute__((address_space(3))) unsigned int*)(l), 16, 0, 17)

static __device__ __forceinline__ void st_u16_sc(u16* p, u16 v) {
  asm volatile("global_store_short %0, %1, off sc0 sc1" :: "v"(p), "v"((unsigned)v) : "memory");
}

// ---------------- prologue kernels (unchanged numerics) ----------------
__launch_bounds__(256)
__global__ void k_selu(const float* __restrict__ z, const float* __restrict__ W1,
                       const float* __restrict__ b1, float* __restrict__ x)
{
  int idx = blockIdx.x * 256 + threadIdx.x;
  if (idx >= BB * LAT) return;
  int b = idx / LAT, i = idx - b * LAT;
  float acc = b1[i];
  const float* zr = z + (size_t)b * LAT;
  for (int k = 0; k < LAT; ++k)
    acc += zr[k] * W1[k * LAT + i];
  const float alpha = 1.6732632423543772f, scale = 1.0507009873554805f;
  x[idx] = scale * (acc > 0.f ? acc : alpha * (expf(acc) - 1.f));
}

__launch_bounds__(256)
__global__ void k_xp1(const float* __restrict__ x, const float* __restrict__ Wi1,
                      const float* __restrict__ bi1, float* __restrict__ xp1)
{
  int nb = blockIdx.x % 9, bb = blockIdx.x / 9;
  int n = nb * 256 + threadIdx.x;
  int b0 = bb * 8;
  if (n >= 2112) return;
  if (n >= 2103) { for (int r = 0; r < 8; ++r) xp1[(size_t)(b0 + r) * 2112 + n] = 0.f; return; }
  float bias = bi1[n];
  float acc[8];
  for (int r = 0; r < 8; ++r) acc[r] = bias;
  for (int k = 0; k < LAT; ++k) {
    float w = Wi1[(size_t)k * 2103 + n];
    #pragma unroll
    for (int r = 0; r < 8; ++r) acc[r] += x[(size_t)(b0 + r) * LAT + k] * w;
  }
  for (int r = 0; r < 8; ++r) xp1[(size_t)(b0 + r) * 2112 + n] = acc[r];
}

__launch_bounds__(256)
__global__ void k_transpose(const float* __restrict__ W, u16* __restrict__ WT,
                            int K, int N, int Kpad, int RowsPad)
{
  int tilesN = RowsPad / 64;
  int tk = blockIdx.x / tilesN, tn = blockIdx.x % tilesN;
  int k0 = tk * 64, n0 = tn * 64;
  __shared__ u16 lds[64][72];
  int tid = threadIdx.x;
  int nl = tid & 63, q = tid >> 6;
  for (int i = 0; i < 16; ++i) {
    int kl = q * 16 + i;
    int k = k0 + kl, n = n0 + nl;
    lds[kl][nl] = (k < K && n < N) ? f2b(W[(size_t)k * N + n]) : (u16)0;
  }
  __syncthreads();
  for (int i = 0; i < 16; ++i) {
    int rl = q * 16 + i;
    WT[(size_t)(n0 + rl) * Kpad + k0 + nl] = lds[nl][rl];
  }
}

__global__ void k_maketab(unsigned int* __restrict__ tab)
{
  if (threadIdx.x != 0 || blockIdx.x != 0) return;
  for (int x = 0; x < 8; ++x) {
    for (int li = 0; li < 32; ++li) {
      unsigned v;
      if (li < 15) {            // GRU3 ksplit
        int t3 = 15 * x + li;
        v = 0xFFFF0000u | (2u << 12) | ((unsigned)(t3 & 7) << 8) | (unsigned)(t3 >> 3);
      } else if (li < 26) {     // GRU2 ksplit
        int t2 = 11 * x + (li - 15);
        v = 0xFFFF0000u | (1u << 12) | ((unsigned)(t2 & 7) << 8) | (unsigned)(t2 >> 3);
      } else if (li < 31) {     // GRU1 pairs
        int pi = 5 * x + (li - 26);
        int i0 = 2 * pi, i1 = 2 * pi + 1;
        unsigned lo = ((unsigned)(i0 & 7) << 8) | (unsigned)(i0 >> 3);
        unsigned hw = ((unsigned)(i1 & 7) << 8) | (unsigned)(i1 >> 3);
        v = lo | (hw << 16);
      } else {
        if (x < 4) {            // OUT pairs
          unsigned lo = (3u << 12) | ((unsigned)(2 * x) << 8);
          unsigned hw = (3u << 12) | ((unsigned)(2 * x + 1) << 8);
          v = lo | (hw << 16);
        } else {                // leftover GRU1 pairs
          int pi = 40 + (x - 4);
          int i0 = 2 * pi, i1 = 2 * pi + 1;
          unsigned lo = ((unsigned)(i0 & 7) << 8) | (unsigned)(i0 >> 3);
          unsigned hw = ((unsigned)(i1 & 7) << 8) | (unsigned)(i1 >> 3);
          v = lo | (hw << 16);
        }
      }
      tab[x + 8 * li] = v;
    }
  }
}

// ---------------- K=32 chunk staging / MFMA (layout identical to r10, verified) ----------------
#define RD32(base, row, q) ((base) + (row) * 64 + ((((q) - ((row) >> 2)) & 3) << 4))

static __device__ __forceinline__ void stage32(
    const u16* __restrict__ A, int As, const u16* __restrict__ W, int Ws, int WH,
    int r0, int j0, int kbase, int wl, int lane, char* buf)
{
  #pragma unroll
  for (int i = 0; i < 4; ++i) {
    const int si = wl * 4 + i;              // wave-uniform
    char* l = buf + si * 1024;
    if (si < 4) {                           // wave 0: A tile (h state -> coherent)
      int slot = si * 64 + lane;
      int row = slot >> 2, gl = slot & 3;
      int gq = (gl + (row >> 2)) & 3;
      GLLA(A + (size_t)(r0 + row) * As + kbase + gq * 8, l);
    } else {                                // waves 1..3: weights (cached)
      int s2 = si * 64 + lane - 256;
      int gate = s2 >> 8, loc = s2 & 255;
      int col = loc >> 2, gl = loc & 3;
      int gq = (gl + (col >> 2)) & 3;
      GLLB(W + ((size_t)gate * WH + j0 + col) * Ws + kbase + gq * 8, l);
    }
  }
}

static __device__ __forceinline__ void stage_out(
    const u16* __restrict__ A, const u16* __restrict__ Wo,
    int r0, int kbase, int wl, int lane, char* buf)
{
  {
    int slot = wl * 64 + lane;              // A slot si=wl
    int row = slot >> 2, gl = slot & 3;
    int gq = (gl + (row >> 2)) & 3;
    GLLA(A + (size_t)(r0 + row) * H3P + kbase + gq * 8, buf + wl * 1024);
  }
  {
    int slot = wl * 64 + lane;              // B slot si=4+wl
    int col = slot >> 2, gl = slot & 3;
    int gq = (gl + (col >> 2)) & 3;
    GLLB(Wo + (size_t)col * H3P + kbase + gq * 8, buf + 4096 + wl * 1024);
  }
}

template<int HACC>
static __device__ __forceinline__ void mm32(const char* gb, int wr, int wc, int m16, int kg,
                                            f32x4 (&acc)[4][2][2])
{
  s16x8 af[2];
  #pragma unroll
  for (int fm = 0; fm < 2; ++fm) {
    int row = wr * 32 + fm * 16 + m16;
    af[fm] = *(const s16x8*)RD32(gb, row, kg);
  }
  #pragma unroll
  for (int g = 0; g < 3; ++g) {
    #pragma unroll
    for (int fn = 0; fn < 2; ++fn) {
      int col = wc * 32 + fn * 16 + m16;
      s16x8 bf = *(const s16x8*)RD32(gb + 4096 + g * 4096, col, kg);
      const int ai = (g == 2) ? HACC : g;
      #pragma unroll
      for (int fm = 0; fm < 2; ++fm)
        acc[ai][fm][fn] = __builtin_amdgcn_mfma_f32_16x16x32_bf16(af[fm], bf, acc[ai][fm][fn], 0, 0, 0);
    }
  }
}

static __device__ __forceinline__ void mm_out(const char* gb, int wr, int wc, int m16, int kg,
                                              f32x4 (&acc2)[2][2])
{
  s16x8 af[2], bf[2];
  #pragma unroll
  for (int fm = 0; fm < 2; ++fm) {
    int row = wr * 32 + fm * 16 + m16;
    af[fm] = *(const s16x8*)RD32(gb, row, kg);
  }
  #pragma unroll
  for (int fn = 0; fn < 2; ++fn) {
    int col = wc * 32 + fn * 16 + m16;
    bf[fn] = *(const s16x8*)RD32(gb + 4096, col, kg);
  }
  #pragma unroll
  for (int fm = 0; fm < 2; ++fm)
    #pragma unroll
    for (int fn = 0; fn < 2; ++fn)
      acc2[fm][fn] = __builtin_amdgcn_mfma_f32_16x16x32_bf16(af[fm], bf[fn], acc2[fm][fn], 0, 0, 0);
}

// GRU two-segment pipeline: 4-buf LDS ring, counted vmcnt, 1 barrier/chunk (= n barriers)
static __device__ __forceinline__ void gru_pipe32(
    const u16* A0, int As0, const u16* W0, int Ws0,
    const u16* A1, int As1, const u16* W1p, int Ws1,
    int WH, int n0, int n1, int k1off,
    int r0, int j0, char* ring, int wl, int lane,
    int wr, int wc, int m16, int kg, f32x4 (&acc)[4][2][2])
{
  const int n = n0 + n1;
#define STG32(C) do { int c_ = (C); char* b_ = ring + (c_ & 3) * 16384; \
    if (c_ < n0) stage32(A0, As0, W0, Ws0, WH, r0, j0, c_ * 32, wl, lane, b_); \
    else         stage32(A1, As1, W1p, Ws1, WH, r0, j0, (c_ - n0) * 32 + k1off, wl, lane, b_); \
  } while (0)
  STG32(0); STG32(1); STG32(2);
  for (int ch = 0; ch < n; ++ch) {
    if (ch + 2 < n)      asm volatile("s_waitcnt vmcnt(8)" ::: "memory");
    else if (ch + 1 < n) asm volatile("s_waitcnt vmcnt(4)" ::: "memory");
    else                 asm volatile("s_waitcnt vmcnt(0)" ::: "memory");
    __builtin_amdgcn_s_barrier();
    if (ch + 3 < n) STG32(ch + 3);
    if (ch < n0) mm32<2>(ring + (ch & 3) * 16384, wr, wc, m16, kg, acc);
    else         mm32<3>(ring + (ch & 3) * 16384, wr, wc, m16, kg, acc);
  }
#undef STG32
}

// ---------------- persistent kernel: 256 blocks x 512 threads, 128KB LDS ----------------
__launch_bounds__(512, 2)
__global__ void k_all(const unsigned int* __restrict__ tab, unsigned int* __restrict__ cnt,
    const u16* __restrict__ WhT1, const u16* __restrict__ WiT2, const u16* __restrict__ WhT2,
    const u16* __restrict__ WiT3, const u16* __restrict__ WhT3, const u16* __restrict__ WoT,
    const float* __restrict__ xp1,
    const float* __restrict__ gbh1,
    const float* __restrict__ gbi2, const float* __restrict__ gbh2,
    const float* __restrict__ gbi3, const float* __restrict__ gbh3,
    const float* __restrict__ bo,
    u16* __restrict__ h1b, u16* __restrict__ h2b, u16* __restrict__ h3b,
    float* __restrict__ out)
{
  extern __shared__ __align__(16) char smem[];      // 131072 dynamic
  const int tid  = threadIdx.x;
  const int wgrp = tid >> 8;
  const int ltid = tid & 255;
  const int lane = tid & 63;
  const int wl   = (tid >> 6) & 3;
  const int wr = wl >> 1, wc = wl & 1;
  const int m16 = lane & 15, kg = lane >> 4;
  char* ring = smem + wgrp * 65536;

  const unsigned e  = tab[blockIdx.x];
  const unsigned lo = e & 0xFFFFu, hi = e >> 16;
  const bool ksplit = (hi == 0xFFFFu);
  const unsigned item = (!ksplit && wgrp == 1) ? hi : lo;
  const int L  = (item >> 12) & 3;
  const int rr = (item >> 8) & 0xF;
  const int cc = item & 0xFF;
  const int r0 = rr * 64, j0 = cc * 64;

  // static per-block GRU config (parity-independent parts)
  int H = 0, As0 = 0, Ws0 = 0, As1 = 0, Ws1 = 0, n0 = 0, n1 = 0, k1off = 0;
  const u16 *A0base = nullptr, *W0p = nullptr, *A1base = nullptr, *W1p = nullptr;
  u16 *hbCbase = nullptr;
  const float *bi = nullptr, *bh = nullptr;
  bool do_epi = true;
  if (L == 0) {
    H = HH1;
    A1base = h1b; As1 = H1P; W1p = WhT1; Ws1 = H1P; n1 = 22;
    bh = gbh1; hbCbase = h1b;
  } else if (L == 1) {
    H = HH1; bi = gbi2; bh = gbh2; hbCbase = h2b;
    if (wgrp == 0) { A0base = h1b; As0 = H1P; W0p = WiT2; Ws0 = H1P; n0 = 22; As1 = H1P; }
    else           { A1base = h2b; As1 = H1P; W1p = WhT2; Ws1 = H1P; n1 = 22; }
    do_epi = (wgrp == 0);
  } else if (L == 2) {
    H = HH3; bi = gbi3; bh = gbh3; hbCbase = h3b;
    if (wgrp == 0) {
      A0base = h2b; As0 = H1P; W0p = WiT3; Ws0 = H1P; n0 = 22;
      A1base = h3b; As1 = H3P; W1p = WhT3; Ws1 = H3P; n1 = 4; k1off = 0;
    } else {
      A1base = h3b; As1 = H3P; W1p = WhT3; Ws1 = H3P; n1 = 26; k1off = 128;
    }
    do_epi = (wgrp == 0);
  }

  // f32 carry in registers (this block owns its tile for all steps)
  f32x4 hp_[2][2];
  { f32x4 z4 = {0.f,0.f,0.f,0.f}; for (int a=0;a<2;++a) for (int b=0;b<2;++b) hp_[a][b]=z4; }

  for (int s = 0; s < NSTEP; ++s) {
    const int t = s - L;
    const int cur = s & 1, prv = cur ^ 1;
    int used = 0;

    if (t >= 0 && t < TT) {
      if (L == 3) {
        // ---- OUT: ring-staged projection + softmax, n=30 chunks ----
        const u16* Ab = h3b + (size_t)prv * BB * H3P;
        f32x4 acc2[2][2];
        { f32x4 z4 = {0.f,0.f,0.f,0.f}; for (int a=0;a<2;++a) for (int b=0;b<2;++b) acc2[a][b]=z4; }
        const int n = H3P / 32;             // 30
        stage_out(Ab, WoT, r0, 0, wl, lane, ring);
        stage_out(Ab, WoT, r0, 32, wl, lane, ring + 8192);
        stage_out(Ab, WoT, r0, 64, wl, lane, ring + 16384);
        for (int ch = 0; ch < n; ++ch) {
          if (ch + 2 < n)      asm volatile("s_waitcnt vmcnt(4)" ::: "memory");
          else if (ch + 1 < n) asm volatile("s_waitcnt vmcnt(2)" ::: "memory");
          else                 asm volatile("s_waitcnt vmcnt(0)" ::: "memory");
          __builtin_amdgcn_s_barrier();
          if (ch + 3 < n) stage_out(Ab, WoT, r0, (ch + 3) * 32, wl, lane, ring + ((ch + 3) & 3) * 8192);
          mm_out(ring + (ch & 3) * 8192, wr, wc, m16, kg, acc2);
        }
        __syncthreads();                    // 31
        float (*ldsL)[68] = (float (*)[68])ring;
        #pragma unroll
        for (int fn = 0; fn < 2; ++fn) {
          int col = wc * 32 + fn * 16 + m16;
          float bov = (col < CH) ? bo[col] : 0.f;
          #pragma unroll
          for (int fm = 0; fm < 2; ++fm)
            #pragma unroll
            for (int ii = 0; ii < 4; ++ii)
              ldsL[wr * 32 + fm * 16 + kg * 4 + ii][col] = acc2[fm][fn][ii] + bov;
        }
        __syncthreads();                    // 32
        if (ltid < 64) {
          int b = r0 + ltid;
          float mx = -1e30f;
          for (int c2 = 0; c2 < CH; ++c2) mx = fmaxf(mx, ldsL[ltid][c2]);
          float sum = 0.f;
          for (int c2 = 0; c2 < CH; ++c2) sum += expf(ldsL[ltid][c2] - mx);
          float inv = 1.f / sum;
          size_t ob = ((size_t)b * TT + t) * CH;
          for (int c2 = 0; c2 < CH; ++c2) out[ob + c2] = expf(ldsL[ltid][c2] - mx) * inv;
        }
        used = STEP_BARS;
      } else {
        // ---- GRU tile ----
        const u16* A0 = A0base ? A0base + (size_t)prv * BB * As0 : nullptr;
        const u16* A1 = A1base ? A1base + (size_t)prv * BB * As1 : nullptr;
        u16* hbC = hbCbase + (size_t)cur * BB * As1;

        f32x4 acc[4][2][2];
        { f32x4 z4 = {0.f,0.f,0.f,0.f};
          for (int g = 0; g < 4; ++g) for (int a = 0; a < 2; ++a) for (int b = 0; b < 2; ++b) acc[g][a][b] = z4; }

        gru_pipe32(A0, As0, W0p, Ws0, A1, As1, W1p, Ws1, H, n0, n1, k1off,
                   r0, j0, ring, wl, lane, wr, wc, m16, kg, acc);
        used = n0 + n1;

        if (ksplit) {
          __syncthreads();
          float* red = (float*)smem;
          if (wgrp == 1) {
            float* b = red + ltid * 64;
            #pragma unroll
            for (int g = 0; g < 4; ++g)
              #pragma unroll
              for (int fm = 0; fm < 2; ++fm)
                #pragma unroll
                for (int fn = 0; fn < 2; ++fn)
                  *(f32x4*)(b + ((g * 2 + fm) * 2 + fn) * 4) = acc[g][fm][fn];
          }
          __syncthreads();
          used += 2;
          if (wgrp == 0) {
            const float* b = red + ltid * 64;
            #pragma unroll
            for (int g = 0; g < 4; ++g)
              #pragma unroll
              for (int fm = 0; fm < 2; ++fm)
                #pragma unroll
                for (int fn = 0; fn < 2; ++fn)
                  acc[g][fm][fn] += *(const f32x4*)(b + ((g * 2 + fm) * 2 + fn) * 4);
          }
        }

        if (do_epi) {
          #pragma unroll
          for (int fn = 0; fn < 2; ++fn) {
            int j = j0 + wc * 32 + fn * 16 + m16;
            if (j >= H) continue;
            float bhz = bh[j], bhr = bh[H + j], bhh = bh[2 * H + j];
            float biz = 0.f, bir = 0.f, bih = 0.f;
            if (L != 0) { biz = bi[j]; bir = bi[H + j]; bih = bi[2 * H + j]; }
            #pragma unroll
            for (int fm = 0; fm < 2; ++fm) {
              #pragma unroll
              for (int ii = 0; ii < 4; ++ii) {
                int row = r0 + wr * 32 + fm * 16 + kg * 4 + ii;
                float az  = acc[0][fm][fn][ii];
                float ar  = acc[1][fm][fn][ii];
                float axh = acc[2][fm][fn][ii];
                float arh = acc[3][fm][fn][ii];
                float pz, pr, xh_, rh_;
                if (L == 0) {
                  const float* xr_ = xp1 + (size_t)row * 2112;
                  pz  = xr_[j] + az + bhz;
                  pr  = xr_[HH1 + j] + ar + bhr;
                  xh_ = xr_[2 * HH1 + j];
                  rh_ = arh + bhh;
                } else {
                  pz  = az + biz + bhz;
                  pr  = ar + bir + bhr;
                  xh_ = axh + bih;
                  rh_ = arh + bhh;
                }
                float zg = 1.f / (1.f + expf(-pz));
                float rg = 1.f / (1.f + expf(-pr));
                float hh = tanhf(xh_ + rg * rh_);
                float hn = zg * hp_[fn][fm][ii] + (1.f - zg) * hh;
                hp_[fn][fm][ii] = hn;
                st_u16_sc(&hbC[(size_t)row * As1 + j], f2b(hn));
              }
            }
          }
        }
      }
    }

    // barrier-count equalization across all blocks/wave-groups
    for (int k = used; k < STEP_BARS; ++k) __syncthreads();

    // global step barrier
    asm volatile("s_waitcnt vmcnt(0)" ::: "memory");
    __syncthreads();
    if (tid == 0) {
      atomicAdd(&cnt[s], 1u);
      int guard = 0;
      while (__hip_atomic_load(&cnt[s], __ATOMIC_RELAXED, __HIP_MEMORY_SCOPE_AGENT) < 256u) {
        __builtin_amdgcn_s_sleep(2);
        if (++guard > (1 << 18)) break;   // bounded spin: fail loud (absmax), never hang
      }
    }
    __syncthreads();
  }
}

// ---------------- host ----------------
extern "C" void kernel_launch(void* const* d_in, const int* in_sizes, int n_in,
                              void* d_out, int out_size, void* d_ws, size_t ws_size,
                              hipStream_t stream)
{
  const float* z    = (const float*)d_in[0];
  const float* W1   = (const float*)d_in[1];
  const float* b1   = (const float*)d_in[2];
  const float* gWi1 = (const float*)d_in[3];
  const float* gWh1 = (const float*)d_in[4];
  const float* gbi1 = (const float*)d_in[5];
  const float* gbh1 = (const float*)d_in[6];
  const float* gWi2 = (const float*)d_in[7];
  const float* gWh2 = (const float*)d_in[8];
  const float* gbi2 = (const float*)d_in[9];
  const float* gbh2 = (const float*)d_in[10];
  const float* gWi3 = (const float*)d_in[11];
  const float* gWh3 = (const float*)d_in[12];
  const float* gbi3 = (const float*)d_in[13];
  const float* gbh3 = (const float*)d_in[14];
  const float* Wo   = (const float*)d_in[15];
  const float* bo   = (const float*)d_in[16];

  char* ws = (char*)d_ws;
  float* x_f  = (float*)(ws + O_X);
  float* xp1  = (float*)(ws + O_XP1);
  u16*   h1b  = (u16*)(ws + O_H1B);
  u16*   h2b  = (u16*)(ws + O_H2B);
  u16*   h3b  = (u16*)(ws + O_H3B);
  u16*   WhT1 = (u16*)(ws + O_WHT1);
  u16*   WiT2 = (u16*)(ws + O_WIT2);
  u16*   WhT2 = (u16*)(ws + O_WHT2);
  u16*   WiT3 = (u16*)(ws + O_WIT3);
  u16*   WhT3 = (u16*)(ws + O_WHT3);
  u16*   WoT  = (u16*)(ws + O_WOT);
  unsigned int* tab = (unsigned int*)(ws + O_TAB);
  unsigned int* cnt = (unsigned int*)(ws + O_CNT);

  hipFuncSetAttribute((const void*)k_all,
                      hipFuncAttributeMaxDynamicSharedMemorySize, 131072);

  hipMemsetAsync(ws + O_H1B, 0, ZERO_HB, stream);
  hipMemsetAsync(ws + O_CNT, 0, NSTEP * 4, stream);

  k_maketab<<<1, 64, 0, stream>>>(tab);
  k_selu<<<(BB * LAT + 255) / 256, 256, 0, stream>>>(z, W1, b1, x_f);
  k_xp1<<<9 * 64, 256, 0, stream>>>(x_f, gWi1, gbi1, xp1);

  k_transpose<<<11 * 33, 256, 0, stream>>>(gWh1, WhT1, 701, 2103, 704, 2112);
  k_transpose<<<11 * 33, 256, 0, stream>>>(gWi2, WiT2, 701, 2103, 704, 2112);
  k_transpose<<<11 * 33, 256, 0, stream>>>(gWh2, WhT2, 701, 2103, 704, 2112);
  k_transpose<<<11 * 44, 256, 0, stream>>>(gWi3, WiT3, 701, 2703, 704, 2816);
  k_transpose<<<15 * 44, 256, 0, stream>>>(gWh3, WhT3, 901, 2703, 960, 2816);
  k_transpose<<<15 * 1, 256, 0, stream>>>(Wo, WoT, 901, 35, 960, 64);

  k_all<<<256, 512, 131072, stream>>>(tab, cnt, WhT1, WiT2, WhT2, WiT3, WhT3, WoT, xp1,
                                      gbh1, gbi2, gbh2, gbi3, gbh3, bo,
                                      h1b, h2b, h3b, (float*)d_out);
}

// Round 12
// 6882.468 us; speedup vs baseline: 1.0166x; 1.0166x over previous
//
#include <hip/hip_runtime.h>
#include <hip/hip_bf16.h>
#include <math.h>

typedef unsigned short u16;
typedef __attribute__((ext_vector_type(4))) float f32x4;
typedef __attribute__((ext_vector_type(8))) short s16x8;

#define BB  512
#define TT  120
#define LAT 292
#define HH1 701
#define HH3 901
#define H1P 704
#define H3P 960
#define CH  35
#define NSTEP (TT + 3)
#define STEP_BARS 32

// ws layout (bytes) — small-mode region (r9-compatible)
static const size_t O_X    = 0;                     // 512*292*4
static const size_t O_XP1  = 598016;                // 512*2112*4 (f32)
static const size_t O_H1F  = 4923392;               // 2*512*704*4 (small mode f32 carry)
static const size_t O_H2F  = 7806976;
static const size_t O_H3F  = 10690560;
static const size_t O_H1B  = 14622720;              // 2-slot bf16 h (small mode)
static const size_t O_H2B  = 16064512;
static const size_t O_H3B  = 17506304;
static const size_t O_WHT1 = 19472384;
static const size_t O_WIT2 = 22446080;
static const size_t O_WHT2 = 25419776;
static const size_t O_WIT3 = 28393472;
static const size_t O_WHT3 = 32358400;
static const size_t O_WOT  = 37765120;
static const size_t O_TAB  = 37888000;              // 256*4
static const size_t O_CNT  = 37889024;              // NSTEP*4
static const size_t ZERO_SMALL = 14548992;          // O_H1F..O_H3B end
// big-mode h rings (one slot per step)
static const size_t S1B = (size_t)BB * H1P * 2;     // 720896
static const size_t S3B = (size_t)BB * H3P * 2;     // 983040
static const size_t O_R1 = 37900288;
static const size_t O_R2 = O_R1 + S1B * NSTEP;      // 126570496
static const size_t O_R3 = O_R2 + S1B * NSTEP;      // 215240704
static const size_t RING_END = O_R3 + S3B * NSTEP;  // 336154624

static __device__ __forceinline__ u16 f2b(float f){
  union { float f; unsigned int i; } v; v.f = f;
  unsigned int x = v.i;
  return (u16)((x + 0x7FFFu + ((x >> 16) & 1u)) >> 16);
}

// async 16B global->LDS, cached path
#define GLL16(g, l) __builtin_amdgcn_global_load_lds( \
    (const __attribute__((address_space(1))) unsigned int*)(g), \
    (__attribute__((address_space(3))) unsigned int*)(l), 16, 0, 0)

static __device__ __forceinline__ void st_u16_sc(u16* p, u16 v) {
  asm volatile("global_store_short %0, %1, off sc0 sc1" :: "v"(p), "v"((unsigned)v) : "memory");
}

// ---------------- prologue kernels ----------------
__launch_bounds__(256)
__global__ void k_selu(const float* __restrict__ z, const float* __restrict__ W1,
                       const float* __restrict__ b1, float* __restrict__ x)
{
  int idx = blockIdx.x * 256 + threadIdx.x;
  if (idx >= BB * LAT) return;
  int b = idx / LAT, i = idx - b * LAT;
  float acc = b1[i];
  const float* zr = z + (size_t)b * LAT;
  for (int k = 0; k < LAT; ++k)
    acc += zr[k] * W1[k * LAT + i];
  const float alpha = 1.6732632423543772f, scale = 1.0507009873554805f;
  x[idx] = scale * (acc > 0.f ? acc : alpha * (expf(acc) - 1.f));
}

__launch_bounds__(256)
__global__ void k_xp1(const float* __restrict__ x, const float* __restrict__ Wi1,
                      const float* __restrict__ bi1, float* __restrict__ xp1)
{
  int nb = blockIdx.x % 9, bb = blockIdx.x / 9;
  int n = nb * 256 + threadIdx.x;
  int b0 = bb * 8;
  if (n >= 2112) return;
  if (n >= 2103) { for (int r = 0; r < 8; ++r) xp1[(size_t)(b0 + r) * 2112 + n] = 0.f; return; }
  float bias = bi1[n];
  float acc[8];
  for (int r = 0; r < 8; ++r) acc[r] = bias;
  for (int k = 0; k < LAT; ++k) {
    float w = Wi1[(size_t)k * 2103 + n];
    #pragma unroll
    for (int r = 0; r < 8; ++r) acc[r] += x[(size_t)(b0 + r) * LAT + k] * w;
  }
  for (int r = 0; r < 8; ++r) xp1[(size_t)(b0 + r) * 2112 + n] = acc[r];
}

__launch_bounds__(256)
__global__ void k_transpose(const float* __restrict__ W, u16* __restrict__ WT,
                            int K, int N, int Kpad, int RowsPad)
{
  int tilesN = RowsPad / 64;
  int tk = blockIdx.x / tilesN, tn = blockIdx.x % tilesN;
  int k0 = tk * 64, n0 = tn * 64;
  __shared__ u16 lds[64][72];
  int tid = threadIdx.x;
  int nl = tid & 63, q = tid >> 6;
  for (int i = 0; i < 16; ++i) {
    int kl = q * 16 + i;
    int k = k0 + kl, n = n0 + nl;
    lds[kl][nl] = (k < K && n < N) ? f2b(W[(size_t)k * N + n]) : (u16)0;
  }
  __syncthreads();
  for (int i = 0; i < 16; ++i) {
    int rl = q * 16 + i;
    WT[(size_t)(n0 + rl) * Kpad + k0 + nl] = lds[nl][rl];
  }
}

__global__ void k_maketab(unsigned int* __restrict__ tab)
{
  if (threadIdx.x != 0 || blockIdx.x != 0) return;
  for (int x = 0; x < 8; ++x) {
    for (int li = 0; li < 32; ++li) {
      unsigned v;
      if (li < 15) {            // GRU3 ksplit
        int t3 = 15 * x + li;
        v = 0xFFFF0000u | (2u << 12) | ((unsigned)(t3 & 7) << 8) | (unsigned)(t3 >> 3);
      } else if (li < 26) {     // GRU2 ksplit
        int t2 = 11 * x + (li - 15);
        v = 0xFFFF0000u | (1u << 12) | ((unsigned)(t2 & 7) << 8) | (unsigned)(t2 >> 3);
      } else if (li < 31) {     // GRU1 pairs
        int pi = 5 * x + (li - 26);
        int i0 = 2 * pi, i1 = 2 * pi + 1;
        unsigned lo = ((unsigned)(i0 & 7) << 8) | (unsigned)(i0 >> 3);
        unsigned hw = ((unsigned)(i1 & 7) << 8) | (unsigned)(i1 >> 3);
        v = lo | (hw << 16);
      } else {
        if (x < 4) {            // OUT pairs
          unsigned lo = (3u << 12) | ((unsigned)(2 * x) << 8);
          unsigned hw = (3u << 12) | ((unsigned)(2 * x + 1) << 8);
          v = lo | (hw << 16);
        } else {                // leftover GRU1 pairs
          int pi = 40 + (x - 4);
          int i0 = 2 * pi, i1 = 2 * pi + 1;
          unsigned lo = ((unsigned)(i0 & 7) << 8) | (unsigned)(i0 >> 3);
          unsigned hw = ((unsigned)(i1 & 7) << 8) | (unsigned)(i1 >> 3);
          v = lo | (hw << 16);
        }
      }
      tab[x + 8 * li] = v;
    }
  }
}

// ---------------- K=32 chunk staging / MFMA ----------------
// chunk buffer 16KB: A [64r][4 gran 16B] at +0; B gate g at 4KB+g*4KB.
// slot (row,gl) holds global granule gq=(gl+(row>>1))&3 -> 8-row bank spread (2-way, free)
#define RD32(base, row, q) ((base) + (row) * 64 + ((((q) - ((row) >> 1)) & 3) << 4))

static __device__ __forceinline__ void stage32(
    const u16* __restrict__ A, int As, const u16* __restrict__ W, int Ws, int WH,
    int r0, int j0, int kbase, int wl, int lane, char* buf)
{
  #pragma unroll
  for (int i = 0; i < 4; ++i) {
    const int si = wl * 4 + i;              // wave-uniform
    char* l = buf + si * 1024;
    if (si < 4) {                           // wave 0: A tile
      int slot = si * 64 + lane;
      int row = slot >> 2, gl = slot & 3;
      int gq = (gl + (row >> 1)) & 3;
      GLL16(A + (size_t)(r0 + row) * As + kbase + gq * 8, l);
    } else {                                // waves 1..3: weights
      int s2 = si * 64 + lane - 256;
      int gate = s2 >> 8, loc = s2 & 255;
      int col = loc >> 2, gl = loc & 3;
      int gq = (gl + (col >> 1)) & 3;
      GLL16(W + ((size_t)gate * WH + j0 + col) * Ws + kbase + gq * 8, l);
    }
  }
}

static __device__ __forceinline__ void stage_out(
    const u16* __restrict__ A, const u16* __restrict__ Wo,
    int r0, int kbase, int wl, int lane, char* buf)
{
  {
    int slot = wl * 64 + lane;
    int row = slot >> 2, gl = slot & 3;
    int gq = (gl + (row >> 1)) & 3;
    GLL16(A + (size_t)(r0 + row) * H3P + kbase + gq * 8, buf + wl * 1024);
  }
  {
    int slot = wl * 64 + lane;
    int col = slot >> 2, gl = slot & 3;
    int gq = (gl + (col >> 1)) & 3;
    GLL16(Wo + (size_t)col * H3P + kbase + gq * 8, buf + 4096 + wl * 1024);
  }
}

template<int HACC>
static __device__ __forceinline__ void mm32(const char* gb, int wr, int wc, int m16, int kg,
                                            f32x4 (&acc)[4][2][2])
{
  s16x8 af[2];
  #pragma unroll
  for (int fm = 0; fm < 2; ++fm) {
    int row = wr * 32 + fm * 16 + m16;
    af[fm] = *(const s16x8*)RD32(gb, row, kg);
  }
  #pragma unroll
  for (int g = 0; g < 3; ++g) {
    #pragma unroll
    for (int fn = 0; fn < 2; ++fn) {
      int col = wc * 32 + fn * 16 + m16;
      s16x8 bf = *(const s16x8*)RD32(gb + 4096 + g * 4096, col, kg);
      const int ai = (g == 2) ? HACC : g;
      #pragma unroll
      for (int fm = 0; fm < 2; ++fm)
        acc[ai][fm][fn] = __builtin_amdgcn_mfma_f32_16x16x32_bf16(af[fm], bf, acc[ai][fm][fn], 0, 0, 0);
    }
  }
}

static __device__ __forceinline__ void mm_out(const char* gb, int wr, int wc, int m16, int kg,
                                              f32x4 (&acc2)[2][2])
{
  s16x8 af[2], bf[2];
  #pragma unroll
  for (int fm = 0; fm < 2; ++fm) {
    int row = wr * 32 + fm * 16 + m16;
    af[fm] = *(const s16x8*)RD32(gb, row, kg);
  }
  #pragma unroll
  for (int fn = 0; fn < 2; ++fn) {
    int col = wc * 32 + fn * 16 + m16;
    bf[fn] = *(const s16x8*)RD32(gb + 4096, col, kg);
  }
  #pragma unroll
  for (int fm = 0; fm < 2; ++fm)
    #pragma unroll
    for (int fn = 0; fn < 2; ++fn)
      acc2[fm][fn] = __builtin_amdgcn_mfma_f32_16x16x32_bf16(af[fm], bf[fn], acc2[fm][fn], 0, 0, 0);
}

// GRU two-segment pipeline: 4-buf LDS ring, counted vmcnt, 1 barrier/chunk
static __device__ __forceinline__ void gru_pipe32(
    const u16* A0, int As0, const u16* W0, int Ws0,
    const u16* A1, int As1, const u16* W1p, int Ws1,
    int WH, int n0, int n1, int k1off,
    int r0, int j0, char* ring, int wl, int lane,
    int wr, int wc, int m16, int kg, f32x4 (&acc)[4][2][2])
{
  const int n = n0 + n1;
#define STG32(C) do { int c_ = (C); char* b_ = ring + (c_ & 3) * 16384; \
    if (c_ < n0) stage32(A0, As0, W0, Ws0, WH, r0, j0, c_ * 32, wl, lane, b_); \
    else         stage32(A1, As1, W1p, Ws1, WH, r0, j0, (c_ - n0) * 32 + k1off, wl, lane, b_); \
  } while (0)
  STG32(0); STG32(1); STG32(2);
  for (int ch = 0; ch < n; ++ch) {
    if (ch + 2 < n)      asm volatile("s_waitcnt vmcnt(8)" ::: "memory");
    else if (ch + 1 < n) asm volatile("s_waitcnt vmcnt(4)" ::: "memory");
    else                 asm volatile("s_waitcnt vmcnt(0)" ::: "memory");
    __builtin_amdgcn_s_barrier();
    if (ch + 3 < n) STG32(ch + 3);
    if (ch < n0) mm32<2>(ring + (ch & 3) * 16384, wr, wc, m16, kg, acc);
    else         mm32<3>(ring + (ch & 3) * 16384, wr, wc, m16, kg, acc);
  }
#undef STG32
}

// ---------------- main kernel: BIG=1 persistent (h ring), BIG=0 per-step launch ----------------
template<int BIG>
__launch_bounds__(512, 2)
__global__ void k_all(int s0, int s1, int D,
    const unsigned int* __restrict__ tab, unsigned int* __restrict__ cnt,
    const u16* __restrict__ WhT1, const u16* __restrict__ WiT2, const u16* __restrict__ WhT2,
    const u16* __restrict__ WiT3, const u16* __restrict__ WhT3, const u16* __restrict__ WoT,
    const float* __restrict__ xp1,
    const float* __restrict__ gbh1,
    const float* __restrict__ gbi2, const float* __restrict__ gbh2,
    const float* __restrict__ gbi3, const float* __restrict__ gbh3,
    const float* __restrict__ bo,
    u16* __restrict__ h1r, u16* __restrict__ h2r, u16* __restrict__ h3r,
    float* __restrict__ h1f, float* __restrict__ h2f, float* __restrict__ h3f,
    float* __restrict__ out)
{
  extern __shared__ __align__(16) char smem[];      // 131072 dynamic
  const int tid  = threadIdx.x;
  const int wgrp = tid >> 8;
  const int ltid = tid & 255;
  const int lane = tid & 63;
  const int wl   = (tid >> 6) & 3;
  const int wr = wl >> 1, wc = wl & 1;
  const int m16 = lane & 15, kg = lane >> 4;
  char* ring = smem + wgrp * 65536;

  const unsigned e  = tab[blockIdx.x];
  const unsigned lo = e & 0xFFFFu, hi = e >> 16;
  const bool ksplit = (hi == 0xFFFFu);
  const unsigned item = (!ksplit && wgrp == 1) ? hi : lo;
  const int L  = (item >> 12) & 3;
  const int rr = (item >> 8) & 0xF;
  const int cc = item & 0xFF;
  const int r0 = rr * 64, j0 = cc * 64;

  // static per-block config
  int H = 0, As0 = 0, Ws0 = 0, As1 = 0, Ws1 = 0, n0 = 0, n1 = 0, k1off = 0;
  const u16 *A0base = nullptr, *W0p = nullptr, *A1base = nullptr, *W1p = nullptr;
  u16 *hbCbase = nullptr;
  float *hfbase = nullptr;
  const float *bi = nullptr, *bh = nullptr;
  bool do_epi = true;
  if (L == 0) {
    H = HH1;
    A1base = h1r; As1 = H1P; W1p = WhT1; Ws1 = H1P; n1 = 22;
    bh = gbh1; hbCbase = h1r; hfbase = h1f;
  } else if (L == 1) {
    H = HH1; bi = gbi2; bh = gbh2; hbCbase = h2r; hfbase = h2f;
    if (wgrp == 0) { A0base = h1r; As0 = H1P; W0p = WiT2; Ws0 = H1P; n0 = 22; As1 = H1P; }
    else           { A1base = h2r; As1 = H1P; W1p = WhT2; Ws1 = H1P; n1 = 22; }
    do_epi = (wgrp == 0);
  } else if (L == 2) {
    H = HH3; bi = gbi3; bh = gbh3; hbCbase = h3r; hfbase = h3f;
    if (wgrp == 0) {
      A0base = h2r; As0 = H1P; W0p = WiT3; Ws0 = H1P; n0 = 22;
      A1base = h3r; As1 = H3P; W1p = WhT3; Ws1 = H3P; n1 = 4; k1off = 0;
    } else {
      A1base = h3r; As1 = H3P; W1p = WhT3; Ws1 = H3P; n1 = 26; k1off = 128;
    }
    do_epi = (wgrp == 0);
  } else {
    As1 = H3P;
  }

  // f32 carry in registers (big mode)
  f32x4 hp_[2][2];
  { f32x4 z4 = {0.f,0.f,0.f,0.f}; for (int a=0;a<2;++a) for (int b=0;b<2;++b) hp_[a][b]=z4; }

  for (int s = s0; s < s1; ++s) {
    const int t = s - L;
    const int cur = s % D, prv = (s + D - 1) % D;
    int used = 0;

    if (t >= 0 && t < TT) {
      if (L == 3) {
        // ---- OUT: ring-staged projection + softmax, n=30 chunks ----
        const u16* Ab = h3r + (size_t)prv * BB * H3P;
        f32x4 acc2[2][2];
        { f32x4 z4 = {0.f,0.f,0.f,0.f}; for (int a=0;a<2;++a) for (int b=0;b<2;++b) acc2[a][b]=z4; }
        const int n = H3P / 32;             // 30
        stage_out(Ab, WoT, r0, 0, wl, lane, ring);
        stage_out(Ab, WoT, r0, 32, wl, lane, ring + 8192);
        stage_out(Ab, WoT, r0, 64, wl, lane, ring + 16384);
        for (int ch = 0; ch < n; ++ch) {
          if (ch + 2 < n)      asm volatile("s_waitcnt vmcnt(4)" ::: "memory");
          else if (ch + 1 < n) asm volatile("s_waitcnt vmcnt(2)" ::: "memory");
          else                 asm volatile("s_waitcnt vmcnt(0)" ::: "memory");
          __builtin_amdgcn_s_barrier();
          if (ch + 3 < n) stage_out(Ab, WoT, r0, (ch + 3) * 32, wl, lane, ring + ((ch + 3) & 3) * 8192);
          mm_out(ring + (ch & 3) * 8192, wr, wc, m16, kg, acc2);
        }
        __syncthreads();                    // 31
        float (*ldsL)[68] = (float (*)[68])ring;
        #pragma unroll
        for (int fn = 0; fn < 2; ++fn) {
          int col = wc * 32 + fn * 16 + m16;
          float bov = (col < CH) ? bo[col] : 0.f;
          #pragma unroll
          for (int fm = 0; fm < 2; ++fm)
            #pragma unroll
            for (int ii = 0; ii < 4; ++ii)
              ldsL[wr * 32 + fm * 16 + kg * 4 + ii][col] = acc2[fm][fn][ii] + bov;
        }
        __syncthreads();                    // 32
        if (ltid < 64) {
          int b = r0 + ltid;
          float mx = -1e30f;
          for (int c2 = 0; c2 < CH; ++c2) mx = fmaxf(mx, ldsL[ltid][c2]);
          float sum = 0.f;
          for (int c2 = 0; c2 < CH; ++c2) sum += expf(ldsL[ltid][c2] - mx);
          float inv = 1.f / sum;
          size_t ob = ((size_t)b * TT + t) * CH;
          for (int c2 = 0; c2 < CH; ++c2) out[ob + c2] = expf(ldsL[ltid][c2] - mx) * inv;
        }
        used = STEP_BARS;
      } else {
        // ---- GRU tile ----
        const u16* A0 = A0base ? A0base + (size_t)prv * BB * As0 : nullptr;
        const u16* A1 = A1base ? A1base + (size_t)prv * BB * As1 : nullptr;
        u16* hbC = hbCbase + (size_t)cur * BB * As1;

        f32x4 acc[4][2][2];
        { f32x4 z4 = {0.f,0.f,0.f,0.f};
          for (int g = 0; g < 4; ++g) for (int a = 0; a < 2; ++a) for (int b = 0; b < 2; ++b) acc[g][a][b] = z4; }

        gru_pipe32(A0, As0, W0p, Ws0, A1, As1, W1p, Ws1, H, n0, n1, k1off,
                   r0, j0, ring, wl, lane, wr, wc, m16, kg, acc);
        used = n0 + n1;

        if (ksplit) {
          __syncthreads();
          float* red = (float*)smem;
          if (wgrp == 1) {
            float* b = red + ltid * 64;
            #pragma unroll
            for (int g = 0; g < 4; ++g)
              #pragma unroll
              for (int fm = 0; fm < 2; ++fm)
                #pragma unroll
                for (int fn = 0; fn < 2; ++fn)
                  *(f32x4*)(b + ((g * 2 + fm) * 2 + fn) * 4) = acc[g][fm][fn];
          }
          __syncthreads();
          used += 2;
          if (wgrp == 0) {
            const float* b = red + ltid * 64;
            #pragma unroll
            for (int g = 0; g < 4; ++g)
              #pragma unroll
              for (int fm = 0; fm < 2; ++fm)
                #pragma unroll
                for (int fn = 0; fn < 2; ++fn)
                  acc[g][fm][fn] += *(const f32x4*)(b + ((g * 2 + fm) * 2 + fn) * 4);
          }
        }

        if (do_epi) {
          float* hfP = nullptr; float* hfC = nullptr;
          if (!BIG) {
            hfP = hfbase + (size_t)prv * BB * As1;
            hfC = hfbase + (size_t)cur * BB * As1;
          }
          #pragma unroll
          for (int fn = 0; fn < 2; ++fn) {
            int j = j0 + wc * 32 + fn * 16 + m16;
            if (j >= H) continue;
            float bhz = bh[j], bhr = bh[H + j], bhh = bh[2 * H + j];
            float biz = 0.f, bir = 0.f, bih = 0.f;
            if (L != 0) { biz = bi[j]; bir = bi[H + j]; bih = bi[2 * H + j]; }
            #pragma unroll
            for (int fm = 0; fm < 2; ++fm) {
              #pragma unroll
              for (int ii = 0; ii < 4; ++ii) {
                int row = r0 + wr * 32 + fm * 16 + kg * 4 + ii;
                float az  = acc[0][fm][fn][ii];
                float ar  = acc[1][fm][fn][ii];
                float axh = acc[2][fm][fn][ii];
                float arh = acc[3][fm][fn][ii];
                float pz, pr, xh_, rh_;
                if (L == 0) {
                  const float* xr_ = xp1 + (size_t)row * 2112;
                  pz  = xr_[j] + az + bhz;
                  pr  = xr_[HH1 + j] + ar + bhr;
                  xh_ = xr_[2 * HH1 + j];
                  rh_ = arh + bhh;
                } else {
                  pz  = az + biz + bhz;
                  pr  = ar + bir + bhr;
                  xh_ = axh + bih;
                  rh_ = arh + bhh;
                }
                float zg = 1.f / (1.f + expf(-pz));
                float rg = 1.f / (1.f + expf(-pr));
                float hh = tanhf(xh_ + rg * rh_);
                float hpv = BIG ? hp_[fn][fm][ii] : hfP[(size_t)row * As1 + j];
                float hn = zg * hpv + (1.f - zg) * hh;
                if (BIG) {
                  hp_[fn][fm][ii] = hn;
                  st_u16_sc(&hbC[(size_t)row * As1 + j], f2b(hn));
                } else {
                  hfC[(size_t)row * As1 + j] = hn;
                  hbC[(size_t)row * As1 + j] = f2b(hn);
                }
              }
            }
          }
        }
      }
    }

    // within-block barrier-count equalization (wave-group slack pairing)
    for (int k = used; k < STEP_BARS; ++k) __syncthreads();

    if (BIG) {
      // global step barrier: drain stores, then arrive+spin
      asm volatile("s_waitcnt vmcnt(0)" ::: "memory");
      __syncthreads();
      if (tid == 0) {
        atomicAdd(&cnt[s], 1u);
        int guard = 0;
        while (__hip_atomic_load(&cnt[s], __ATOMIC_RELAXED, __HIP_MEMORY_SCOPE_AGENT) < 256u) {
          __builtin_amdgcn_s_sleep(2);
          if (++guard > (1 << 18)) break;   // fail loud, never hang
        }
      }
      __syncthreads();
    }
  }
}

// ---------------- host ----------------
extern "C" void kernel_launch(void* const* d_in, const int* in_sizes, int n_in,
                              void* d_out, int out_size, void* d_ws, size_t ws_size,
                              hipStream_t stream)
{
  const float* z    = (const float*)d_in[0];
  const float* W1   = (const float*)d_in[1];
  const float* b1   = (const float*)d_in[2];
  const float* gWi1 = (const float*)d_in[3];
  const float* gWh1 = (const float*)d_in[4];
  const float* gbi1 = (const float*)d_in[5];
  const float* gbh1 = (const float*)d_in[6];
  const float* gWi2 = (const float*)d_in[7];
  const float* gWh2 = (const float*)d_in[8];
  const float* gbi2 = (const float*)d_in[9];
  const float* gbh2 = (const float*)d_in[10];
  const float* gWi3 = (const float*)d_in[11];
  const float* gWh3 = (const float*)d_in[12];
  const float* gbi3 = (const float*)d_in[13];
  const float* gbh3 = (const float*)d_in[14];
  const float* Wo   = (const float*)d_in[15];
  const float* bo   = (const float*)d_in[16];

  char* ws = (char*)d_ws;
  float* x_f  = (float*)(ws + O_X);
  float* xp1  = (float*)(ws + O_XP1);
  u16*   WhT1 = (u16*)(ws + O_WHT1);
  u16*   WiT2 = (u16*)(ws + O_WIT2);
  u16*   WhT2 = (u16*)(ws + O_WHT2);
  u16*   WiT3 = (u16*)(ws + O_WIT3);
  u16*   WhT3 = (u16*)(ws + O_WHT3);
  u16*   WoT  = (u16*)(ws + O_WOT);
  unsigned int* tab = (unsigned int*)(ws + O_TAB);
  unsigned int* cnt = (unsigned int*)(ws + O_CNT);

  const bool big = (ws_size >= RING_END);

  hipFuncSetAttribute((const void*)k_all<1>,
                      hipFuncAttributeMaxDynamicSharedMemorySize, 131072);
  hipFuncSetAttribute((const void*)k_all<0>,
                      hipFuncAttributeMaxDynamicSharedMemorySize, 131072);

  k_maketab<<<1, 64, 0, stream>>>(tab);
  k_selu<<<(BB * LAT + 255) / 256, 256, 0, stream>>>(z, W1, b1, x_f);
  k_xp1<<<9 * 64, 256, 0, stream>>>(x_f, gWi1, gbi1, xp1);

  k_transpose<<<11 * 33, 256, 0, stream>>>(gWh1, WhT1, 701, 2103, 704, 2112);
  k_transpose<<<11 * 33, 256, 0, stream>>>(gWi2, WiT2, 701, 2103, 704, 2112);
  k_transpose<<<11 * 33, 256, 0, stream>>>(gWh2, WhT2, 701, 2103, 704, 2112);
  k_transpose<<<11 * 44, 256, 0, stream>>>(gWi3, WiT3, 701, 2703, 704, 2816);
  k_transpose<<<15 * 44, 256, 0, stream>>>(gWh3, WhT3, 901, 2703, 960, 2816);
  k_transpose<<<15 * 1, 256, 0, stream>>>(Wo, WoT, 901, 35, 960, 64);

  if (big) {
    u16* h1r = (u16*)(ws + O_R1);
    u16* h2r = (u16*)(ws + O_R2);
    u16* h3r = (u16*)(ws + O_R3);
    hipMemsetAsync(ws + O_CNT, 0, NSTEP * 4, stream);
    hipMemsetAsync(ws + O_R1 + (size_t)(NSTEP - 1) * S1B, 0, S1B, stream);  // h1 slot read at s=0
    hipMemsetAsync(ws + O_R2, 0, S1B, stream);                              // h2 slot 0 (read s=1)
    hipMemsetAsync(ws + O_R3 + S3B, 0, S3B, stream);                        // h3 slot 1 (read s=2)
    k_all<1><<<256, 512, 131072, stream>>>(0, NSTEP, NSTEP, tab, cnt,
        WhT1, WiT2, WhT2, WiT3, WhT3, WoT, xp1,
        gbh1, gbi2, gbh2, gbi3, gbh3, bo,
        h1r, h2r, h3r, nullptr, nullptr, nullptr, (float*)d_out);
  } else {
    u16* h1b = (u16*)(ws + O_H1B);
    u16* h2b = (u16*)(ws + O_H2B);
    u16* h3b = (u16*)(ws + O_H3B);
    float* h1f = (float*)(ws + O_H1F);
    float* h2f = (float*)(ws + O_H2F);
    float* h3f = (float*)(ws + O_H3F);
    hipMemsetAsync(ws + O_H1F, 0, ZERO_SMALL, stream);
    for (int s = 0; s < NSTEP; ++s)
      k_all<0><<<256, 512, 131072, stream>>>(s, s + 1, 2, tab, cnt,
          WhT1, WiT2, WhT2, WiT3, WhT3, WoT, xp1,
          gbh1, gbi2, gbh2, gbi3, gbh3, bo,
          h1b, h2b, h3b, h1f, h2f, h3f, (float*)d_out);
  }
}